// Round 9
// baseline (565.145 us; speedup 1.0000x reference)
//
#include <hip/hip_runtime.h>
#include <hip/hip_bf16.h>
#include <math.h>

#define BB  64
#define CC  64
#define LL  720
#define LLP 736           // 720 padded to multiple of 32
#define DD  512
#define PP  336
#define P2C 168
#define HH  512
#define MM  (BB*CC)       // 4096

typedef _Float16 f16x8 __attribute__((ext_vector_type(8)));
typedef float    f32x4 __attribute__((ext_vector_type(4)));

// ---------------------------------------------------------------------------
// Batched weight convert: fp32 W[K][N] -> fp16 hi/lo planes Wt[N][Kpad]
// (transposed; hi = f16(w), lo = f16(w - hi); K-pad zeroed)
struct WDesc { const float* src; _Float16* dstHi; _Float16* dstLo;
               int K, N, Kpad, tbase, tilesN; };
struct WTab  { WDesc d[12]; };

__global__ __launch_bounds__(256) void k_convert(WTab tab) {
  __shared__ float tile[16][17];
  const int bid = blockIdx.x;
  int wi = 0;
#pragma unroll
  for (int i = 1; i < 12; ++i) if (bid >= tab.d[i].tbase) wi = i;
  const WDesc d = tab.d[wi];
  const int lt = bid - d.tbase;
  const int tk = lt / d.tilesN, tn = lt % d.tilesN;
  const int k0 = tk * 16, n0 = tn * 16;
  const int tx = threadIdx.x & 15, ty = threadIdx.x >> 4;
  float v = 0.f;
  if (n0 + tx < d.N) v = d.src[(size_t)(k0 + ty) * d.N + n0 + tx];
  tile[ty][tx] = v;
  __syncthreads();
  if (n0 + ty < d.N) {
    const float w = tile[tx][ty];
    const _Float16 h = (_Float16)w;
    const _Float16 l = (_Float16)(w - (float)h);
    const size_t base = (size_t)(n0 + ty) * d.Kpad;
    d.dstHi[base + k0 + tx] = h;
    d.dstLo[base + k0 + tx] = l;
    if (d.Kpad != d.K && k0 + 16 == d.K) {
      d.dstHi[base + d.K + tx] = (_Float16)0.f;
      d.dstLo[base + d.K + tx] = (_Float16)0.f;
    }
  }
}

// ---------------------------------------------------------------------------
// x_bsd [B][L][C] -> x hi/lo [M][736] (pad cols zeroed)
__global__ __launch_bounds__(256) void k_xpose(const float* __restrict__ xbsd,
                                               _Float16* __restrict__ xhi,
                                               _Float16* __restrict__ xlo) {
  __shared__ float tile[16][17];
  const int b = blockIdx.z, l0 = blockIdx.x * 16, c0 = blockIdx.y * 16;
  const int tx = threadIdx.x, ty = threadIdx.y;
  tile[ty][tx] = xbsd[(size_t)b * LL * CC + (size_t)(l0 + ty) * CC + c0 + tx];
  __syncthreads();
  const float v = tile[tx][ty];
  const _Float16 h = (_Float16)v;
  const _Float16 l = (_Float16)(v - (float)h);
  const size_t m = (size_t)b * CC + c0 + ty;
  xhi[m * LLP + l0 + tx] = h;
  xlo[m * LLP + l0 + tx] = l;
  if (l0 == 704) {
    xhi[m * LLP + 720 + tx] = (_Float16)0.f;
    xlo[m * LLP + 720 + tx] = (_Float16)0.f;
  }
}

// ---------------------------------------------------------------------------
// Split-3 MFMA GEMM v3: BM=128, BN=64, BK=32; 256 threads = 4 waves in a
// 2x2 grid. Wave (wr,wc) owns rows [wr*64,+64) x cols [wc*32,+32), computing
// BOTH S and T for those cols (dual). Register double-buffered staging hides
// global latency across the barrier. Vin/out pointers intentionally NOT
// __restrict__: in-place affines alias them (same element per thread).
// EPI: 0 = affine (dual s/t; out = Vin*vscale*exp(tanh(S)) + T)
//      1 = gelu  (single; hi/lo out)
//      2 = raw   (single; transposed fp32 out)
template<int EPI, bool DUAL, bool VIN16, bool OUT_T>
__global__ __launch_bounds__(256, 3)
void k_gemm(const _Float16* __restrict__ Ahi, const _Float16* __restrict__ Alo, int lda,
            const _Float16* __restrict__ Whi, const _Float16* __restrict__ Wlo, int ldw,
            const float* Vin32, const _Float16* VinHi,
            const _Float16* VinLo, int ldv, float vscale,
            float* outT32,
            _Float16* outHi, _Float16* outLo, int ldo,
            int Kp, int Nv) {
  constexpr int NB = DUAL ? 128 : 64;
  constexpr int BP = NB / 64;           // B staging rounds per plane
  __shared__ _Float16 AsHi[128 * 40];
  __shared__ _Float16 AsLo[128 * 40];
  __shared__ _Float16 BsHi[NB * 40];
  __shared__ _Float16 BsLo[NB * 40];
  const int m0 = blockIdx.y * 128;
  const int n0 = blockIdx.x * 64;
  const int tid = threadIdx.x;
  const int w = tid >> 6, lane = tid & 63, q = lane >> 4, r = lane & 15;
  const int wr = (w & 1) * 64, wc = (w >> 1) * 32;

  f32x4 accS[4][2] = {};
  f32x4 accT[4][2] = {};

  const int arow0 = tid >> 2, aseg = tid & 3;   // A staging: (row, 8-half seg)
  const int bidx_row = tid >> 2, bidx_seg = tid & 3;
  const int bnr  = bidx_row & 63;
  const bool bok = (n0 + bnr) < Nv;

  f16x8 rAh[2], rAl[2], rBh[BP], rBl[BP];

  // ---- prologue stage (k0 = 0), inlined
#pragma unroll
  for (int p = 0; p < 2; ++p) {
    const size_t off = (size_t)(m0 + arow0 + p * 64) * lda + aseg * 8;
    rAh[p] = *(const f16x8*)(Ahi + off);
    rAl[p] = *(const f16x8*)(Alo + off);
  }
#pragma unroll
  for (int p = 0; p < BP; ++p) {
    const int row = (p * 256 + tid) >> 2;
    const int nr  = row & 63;
    const int wrow = (row < 64) ? (n0 + nr) : (Nv + n0 + nr);
    f16x8 vh = {0, 0, 0, 0, 0, 0, 0, 0};
    f16x8 vl = {0, 0, 0, 0, 0, 0, 0, 0};
    if ((n0 + nr) < Nv) {
      const size_t off = (size_t)wrow * ldw + bidx_seg * 8;
      vh = *(const f16x8*)(Whi + off);
      vl = *(const f16x8*)(Wlo + off);
    }
    rBh[p] = vh; rBl[p] = vl;
  }

  const int nk = Kp >> 5;
  for (int kc = 0; kc < nk; ++kc) {
    // commit staged regs to LDS
#pragma unroll
    for (int p = 0; p < 2; ++p) {
      const int row = arow0 + p * 64;
      *(f16x8*)(&AsHi[row * 40 + aseg * 8]) = rAh[p];
      *(f16x8*)(&AsLo[row * 40 + aseg * 8]) = rAl[p];
    }
#pragma unroll
    for (int p = 0; p < BP; ++p) {
      const int idx = p * 256 + tid;
      const int row = idx >> 2, seg = idx & 3;
      *(f16x8*)(&BsHi[row * 40 + seg * 8]) = rBh[p];
      *(f16x8*)(&BsLo[row * 40 + seg * 8]) = rBl[p];
    }
    __syncthreads();

    // prefetch next k-tile into regs (overlaps MFMA below), inlined
    if (kc + 1 < nk) {
      const int k0n = (kc + 1) << 5;
#pragma unroll
      for (int p = 0; p < 2; ++p) {
        const size_t off = (size_t)(m0 + arow0 + p * 64) * lda + k0n + aseg * 8;
        rAh[p] = *(const f16x8*)(Ahi + off);
        rAl[p] = *(const f16x8*)(Alo + off);
      }
#pragma unroll
      for (int p = 0; p < BP; ++p) {
        const int row = (p * 256 + tid) >> 2;
        const int nr  = row & 63;
        const int wrow = (row < 64) ? (n0 + nr) : (Nv + n0 + nr);
        f16x8 vh = {0, 0, 0, 0, 0, 0, 0, 0};
        f16x8 vl = {0, 0, 0, 0, 0, 0, 0, 0};
        if ((n0 + nr) < Nv) {
          const size_t off = (size_t)wrow * ldw + k0n + bidx_seg * 8;
          vh = *(const f16x8*)(Whi + off);
          vl = *(const f16x8*)(Wlo + off);
        }
        rBh[p] = vh; rBl[p] = vl;
      }
    }

    f16x8 ah[4], al[4];
#pragma unroll
    for (int rt = 0; rt < 4; ++rt) {
      ah[rt] = *(const f16x8*)(&AsHi[(wr + rt * 16 + r) * 40 + q * 8]);
      al[rt] = *(const f16x8*)(&AsLo[(wr + rt * 16 + r) * 40 + q * 8]);
    }
#pragma unroll
    for (int ct = 0; ct < 2; ++ct) {
      const int brow = wc + ct * 16 + r;
      const f16x8 bh = *(const f16x8*)(&BsHi[brow * 40 + q * 8]);
      const f16x8 bl = *(const f16x8*)(&BsLo[brow * 40 + q * 8]);
#pragma unroll
      for (int rt = 0; rt < 4; ++rt) {
        accS[rt][ct] = __builtin_amdgcn_mfma_f32_16x16x32_f16(ah[rt], bh, accS[rt][ct], 0, 0, 0);
        accS[rt][ct] = __builtin_amdgcn_mfma_f32_16x16x32_f16(al[rt], bh, accS[rt][ct], 0, 0, 0);
        accS[rt][ct] = __builtin_amdgcn_mfma_f32_16x16x32_f16(ah[rt], bl, accS[rt][ct], 0, 0, 0);
      }
      if (DUAL) {
        const f16x8 chh = *(const f16x8*)(&BsHi[(64 + brow) * 40 + q * 8]);
        const f16x8 cll = *(const f16x8*)(&BsLo[(64 + brow) * 40 + q * 8]);
#pragma unroll
        for (int rt = 0; rt < 4; ++rt) {
          accT[rt][ct] = __builtin_amdgcn_mfma_f32_16x16x32_f16(ah[rt], chh, accT[rt][ct], 0, 0, 0);
          accT[rt][ct] = __builtin_amdgcn_mfma_f32_16x16x32_f16(al[rt], chh, accT[rt][ct], 0, 0, 0);
          accT[rt][ct] = __builtin_amdgcn_mfma_f32_16x16x32_f16(ah[rt], cll, accT[rt][ct], 0, 0, 0);
        }
      }
    }
    __syncthreads();
  }

  // epilogue: m = m0 + wr + rt*16 + q*4 + g,  n = n0 + wc + ct*16 + r
#pragma unroll
  for (int rt = 0; rt < 4; ++rt) {
    const int mb = m0 + wr + rt * 16 + q * 4;
#pragma unroll
    for (int ct = 0; ct < 2; ++ct) {
      const int n = n0 + wc + ct * 16 + r;
      if (n >= Nv) continue;
      if (EPI == 2) {
        *(f32x4*)(outT32 + (size_t)n * MM + mb) = accS[rt][ct];
      } else if (EPI == 1) {
#pragma unroll
        for (int g = 0; g < 4; ++g) {
          const int m = mb + g;
          const float v = accS[rt][ct][g];
          const float o = 0.5f * v * (1.0f + tanhf(0.7978845608028654f * (v + 0.044715f * v * v * v)));
          const _Float16 h = (_Float16)o;
          outHi[(size_t)m * ldo + n] = h;
          outLo[(size_t)m * ldo + n] = (_Float16)(o - (float)h);
        }
      } else {
        f32x4 o;
#pragma unroll
        for (int g = 0; g < 4; ++g) {
          const int m = mb + g;
          float v;
          if (VIN16) {
            v = (float)VinHi[(size_t)m * ldv + n] + (float)VinLo[(size_t)m * ldv + n];
          } else {
            v = Vin32[(size_t)m * ldv + n];
          }
          const float s = expf(tanhf(accS[rt][ct][g]));
          o[g] = v * vscale * s + accT[rt][ct][g];
        }
        if (OUT_T) {
          *(f32x4*)(outT32 + (size_t)n * MM + mb) = o;
        } else {
#pragma unroll
          for (int g = 0; g < 4; ++g) {
            const int m = mb + g;
            const _Float16 h = (_Float16)o[g];
            outHi[(size_t)m * ldo + n] = h;
            outLo[(size_t)m * ldo + n] = (_Float16)(o[g] - (float)h);
          }
        }
      }
    }
  }
}

// ---------------------------------------------------------------------------
// Final elementwise: Pt[840][M] (theta raw | S raw | T), yT[336][M] -> out[B][336][C]
__global__ __launch_bounds__(256) void k_final(const float* __restrict__ Pt,
                                               const float* __restrict__ yT,
                                               const float* __restrict__ Ay,
                                               const float* __restrict__ By,
                                               float* __restrict__ out) {
  const int c = threadIdx.x;                       // 0..63
  const int j = blockIdx.x * 4 + threadIdx.y;      // 0..167
  const int b = blockIdx.y;
  const int m = b * 64 + c;
  const float th = 3.14159265358979323846f * tanhf(Pt[(size_t)j * MM + m]);
  const float sc0 = expf(tanhf(Pt[(size_t)(168 + 2 * j) * MM + m]));
  const float sc1 = expf(tanhf(Pt[(size_t)(169 + 2 * j) * MM + m]));
  const float t0 = Pt[(size_t)(504 + 2 * j) * MM + m];
  const float t1 = Pt[(size_t)(505 + 2 * j) * MM + m];
  const float re = yT[(size_t)(2 * j) * MM + m];
  const float im = yT[(size_t)(2 * j + 1) * MM + m];
  const float a = Ay[c * P2C + j], bb = By[c * P2C + j];
  const float rn = rsqrtf(a * a + bb * bb);
  const float ca = a * rn, cb = bb * rn;
  float s1v, c1;
  sincosf(th, &s1v, &c1);
  const float r1 = c1 * re - s1v * im, i1 = s1v * re + c1 * im;   // rot
  const float r2 = ca * r1 - cb * i1,  i2 = cb * r1 + ca * i1;    // koop
  const float r3 = r2 * sc0,           i3 = i2 * sc1;             // * scale
  const float r4 = ca * r3 + cb * i3,  i4 = ca * i3 - cb * r3;    // koop^-1
  const float r5 = c1 * r4 + s1v * i4, i5 = c1 * i4 - s1v * r4;   // rot^-1
  out[(size_t)b * PP * CC + (size_t)(2 * j) * CC + c]     = r5 + t0;
  out[(size_t)b * PP * CC + (size_t)(2 * j + 1) * CC + c] = i5 + t1;
}

// ---------------------------------------------------------------------------
extern "C" void kernel_launch(void* const* d_in, const int* in_sizes, int n_in,
                              void* d_out, int out_size, void* d_ws, size_t ws_size,
                              hipStream_t stream) {
  const float* x_bsd   = (const float*)d_in[0];
  const float* z0      = (const float*)d_in[1];
  const float* y0      = (const float*)d_in[2];
  const float* W_h     = (const float*)d_in[3];
  const float* W_ssz   = (const float*)d_in[4];
  const float* W_xz_v2 = (const float*)d_in[5];
  const float* W_xz_v3 = (const float*)d_in[6];
  const float* W_xz_v4 = (const float*)d_in[7];
  const float* W_xz_v5 = (const float*)d_in[8];
  const float* W_zx_v0 = (const float*)d_in[9];
  const float* W_zx_v2 = (const float*)d_in[10];
  const float* W_zx_v3 = (const float*)d_in[11];
  // d_in[12] = W_zx_v5: dead (x never read after), skipped
  const float* W_zy_v4 = (const float*)d_in[13];
  const float* W_rot   = (const float*)d_in[14];
  const float* W_koo   = (const float*)d_in[15];
  const float* a_y     = (const float*)d_in[16];
  const float* b_y     = (const float*)d_in[17];
  float* out = (float*)d_out;

  char* p = (char*)d_ws;
  auto alloc = [&](size_t bytes) -> void* {
    void* r = (void*)p; p += (bytes + 255) & ~(size_t)255; return r;
  };
  float*    yT  = (float*)alloc((size_t)PP * MM * 4);
  float*    Pt  = (float*)alloc((size_t)(P2C * 5) * MM * 4);  // 840 rows
  _Float16* xhi = (_Float16*)alloc((size_t)MM * LLP * 2);
  _Float16* xlo = (_Float16*)alloc((size_t)MM * LLP * 2);
  _Float16* zhi = (_Float16*)alloc((size_t)MM * DD * 2);
  _Float16* zlo = (_Float16*)alloc((size_t)MM * DD * 2);
  _Float16* hhi = (_Float16*)alloc((size_t)MM * HH * 2);
  _Float16* hlo = (_Float16*)alloc((size_t)MM * HH * 2);
  auto wpair = [&](size_t elems, _Float16** lo) -> _Float16* {
    _Float16* hi = (_Float16*)alloc(elems * 2);
    *lo = (_Float16*)alloc(elems * 2);
    return hi;
  };
  _Float16 *tWhL, *tWsszL, *tWxz2L, *tWxz3L, *tWxz4L, *tWxz5L;
  _Float16 *tWzx0L, *tWzx2L, *tWzx3L, *tWzyL, *tWcatL;
  _Float16* tWh   = wpair((size_t)HH * LLP, &tWhL);
  _Float16* tWssz = wpair((size_t)(2*DD) * DD, &tWsszL);
  _Float16* tWxz2 = wpair((size_t)(2*DD) * LLP, &tWxz2L);
  _Float16* tWxz3 = wpair((size_t)(2*DD) * LLP, &tWxz3L);
  _Float16* tWxz4 = wpair((size_t)(2*DD) * LLP, &tWxz4L);
  _Float16* tWxz5 = wpair((size_t)(2*DD) * LLP, &tWxz5L);
  _Float16* tWzx0 = wpair((size_t)(2*LL) * DD, &tWzx0L);
  _Float16* tWzx2 = wpair((size_t)(2*LL) * DD, &tWzx2L);
  _Float16* tWzx3 = wpair((size_t)(2*LL) * DD, &tWzx3L);
  _Float16* tWzy  = wpair((size_t)(2*PP) * DD, &tWzyL);
  _Float16* tWcat = wpair((size_t)(P2C*5) * DD, &tWcatL);   // [840][512]

  // ---- weight convert table
  WTab tab;
  int base = 0;
  auto put = [&](int i, const float* src, _Float16* dh, _Float16* dl,
                 int K, int N, int Kpad) {
    const int tN = (N + 15) / 16;
    tab.d[i] = WDesc{src, dh, dl, K, N, Kpad, base, tN};
    base += ((K + 15) / 16) * tN;
  };
  put(0,  W_h,     tWh,   tWhL,   LL, HH,   LLP);
  put(1,  W_ssz,   tWssz, tWsszL, DD, 2*DD, DD);
  put(2,  W_xz_v2, tWxz2, tWxz2L, LL, 2*DD, LLP);
  put(3,  W_xz_v3, tWxz3, tWxz3L, LL, 2*DD, LLP);
  put(4,  W_xz_v4, tWxz4, tWxz4L, LL, 2*DD, LLP);
  put(5,  W_xz_v5, tWxz5, tWxz5L, LL, 2*DD, LLP);
  put(6,  W_zx_v0, tWzx0, tWzx0L, DD, 2*LL, DD);
  put(7,  W_zx_v2, tWzx2, tWzx2L, DD, 2*LL, DD);
  put(8,  W_zx_v3, tWzx3, tWzx3L, DD, 2*LL, DD);
  put(9,  W_zy_v4, tWzy,  tWzyL,  DD, 2*PP, DD);
  put(10, W_rot,   tWcat, tWcatL, DD, P2C,  DD);
  put(11, W_koo,   tWcat + (size_t)P2C * DD, tWcatL + (size_t)P2C * DD, DD, 2*PP, DD);
  const int total_tiles = base;

  k_convert<<<dim3(total_tiles), dim3(256), 0, stream>>>(tab);
  k_xpose<<<dim3(45, 4, 64), dim3(16, 16), 0, stream>>>(x_bsd, xhi, xlo);

  const dim3 blk(256);
  // h = gelu(x @ W_h)
  k_gemm<1, false, false, false><<<dim3(8, 32), blk, 0, stream>>>(
      xhi, xlo, LLP, tWh, tWhL, LLP,
      nullptr, nullptr, nullptr, 0, 0.f, nullptr, hhi, hlo, HH, LLP, HH);
  // z = affine(z0*0.1, h, W_ssz)
  k_gemm<0, true, false, false><<<dim3(8, 32), blk, 0, stream>>>(
      hhi, hlo, HH, tWssz, tWsszL, DD,
      z0, nullptr, nullptr, DD, 0.1f, nullptr, zhi, zlo, DD, DD, DD);
  // x = affine(x, z, W_zx_v0)
  k_gemm<0, true, true, false><<<dim3(12, 32), blk, 0, stream>>>(
      zhi, zlo, DD, tWzx0, tWzx0L, DD,
      nullptr, xhi, xlo, LLP, 1.f, nullptr, xhi, xlo, LLP, DD, LL);
  // z = affine(z, x, W_xz_v2)
  k_gemm<0, true, true, false><<<dim3(8, 32), blk, 0, stream>>>(
      xhi, xlo, LLP, tWxz2, tWxz2L, LLP,
      nullptr, zhi, zlo, DD, 1.f, nullptr, zhi, zlo, DD, LLP, DD);
  // x = affine(x, z, W_zx_v2)
  k_gemm<0, true, true, false><<<dim3(12, 32), blk, 0, stream>>>(
      zhi, zlo, DD, tWzx2, tWzx2L, DD,
      nullptr, xhi, xlo, LLP, 1.f, nullptr, xhi, xlo, LLP, DD, LL);
  // z = affine(z, x, W_xz_v3)
  k_gemm<0, true, true, false><<<dim3(8, 32), blk, 0, stream>>>(
      xhi, xlo, LLP, tWxz3, tWxz3L, LLP,
      nullptr, zhi, zlo, DD, 1.f, nullptr, zhi, zlo, DD, LLP, DD);
  // x = affine(x, z, W_zx_v3)
  k_gemm<0, true, true, false><<<dim3(12, 32), blk, 0, stream>>>(
      zhi, zlo, DD, tWzx3, tWzx3L, DD,
      nullptr, xhi, xlo, LLP, 1.f, nullptr, xhi, xlo, LLP, DD, LL);
  // z = affine(z, x, W_xz_v4)
  k_gemm<0, true, true, false><<<dim3(8, 32), blk, 0, stream>>>(
      xhi, xlo, LLP, tWxz4, tWxz4L, LLP,
      nullptr, zhi, zlo, DD, 1.f, nullptr, zhi, zlo, DD, LLP, DD);
  // yT = affine(y0*0.1, z, W_zy_v4)  [transposed fp32 out]
  k_gemm<0, true, false, true><<<dim3(6, 32), blk, 0, stream>>>(
      zhi, zlo, DD, tWzy, tWzyL, DD,
      y0, nullptr, nullptr, PP, 0.1f, yT, nullptr, nullptr, 0, DD, PP);
  // z = affine(z, x, W_xz_v5)
  k_gemm<0, true, true, false><<<dim3(8, 32), blk, 0, stream>>>(
      xhi, xlo, LLP, tWxz5, tWxz5L, LLP,
      nullptr, zhi, zlo, DD, 1.f, nullptr, zhi, zlo, DD, LLP, DD);
  // Pt = z @ [W_rot | W_koo]  (raw, transposed fp32 out): 840 cols
  k_gemm<2, false, false, true><<<dim3(14, 32), blk, 0, stream>>>(
      zhi, zlo, DD, tWcat, tWcatL, DD,
      nullptr, nullptr, nullptr, 0, 0.f, Pt, nullptr, nullptr, 0, DD, P2C * 5);
  // final elementwise + transposed store
  k_final<<<dim3(42, 64), dim3(64, 4), 0, stream>>>(Pt, yT, a_y, b_y, out);
}

// Round 10
// 491.650 us; speedup vs baseline: 1.1495x; 1.1495x over previous
//
#include <hip/hip_runtime.h>
#include <hip/hip_bf16.h>
#include <math.h>

#define BB  64
#define CC  64
#define LL  720
#define LLP 736           // 720 padded to multiple of 32
#define DD  512
#define PP  336
#define P2C 168
#define HH  512
#define MM  (BB*CC)       // 4096

typedef _Float16 f16x8 __attribute__((ext_vector_type(8)));
typedef float    f32x4 __attribute__((ext_vector_type(4)));

#define GLDS16(g, l) __builtin_amdgcn_global_load_lds( \
    (const __attribute__((address_space(1))) void*)(g), \
    (__attribute__((address_space(3))) void*)(l), 16, 0, 0)

// ---------------------------------------------------------------------------
// Batched weight convert: fp32 W[K][N] -> fp16 hi/lo planes Wt[N][Kpad]
// (transposed; hi = f16(w), lo = f16(w - hi); K-pad zeroed)
struct WDesc { const float* src; _Float16* dstHi; _Float16* dstLo;
               int K, N, Kpad, tbase, tilesN; };
struct WTab  { WDesc d[12]; };

__global__ __launch_bounds__(256) void k_convert(WTab tab) {
  __shared__ float tile[16][17];
  const int bid = blockIdx.x;
  int wi = 0;
#pragma unroll
  for (int i = 1; i < 12; ++i) if (bid >= tab.d[i].tbase) wi = i;
  const WDesc d = tab.d[wi];
  const int lt = bid - d.tbase;
  const int tk = lt / d.tilesN, tn = lt % d.tilesN;
  const int k0 = tk * 16, n0 = tn * 16;
  const int tx = threadIdx.x & 15, ty = threadIdx.x >> 4;
  float v = 0.f;
  if (n0 + tx < d.N) v = d.src[(size_t)(k0 + ty) * d.N + n0 + tx];
  tile[ty][tx] = v;
  __syncthreads();
  if (n0 + ty < d.N) {
    const float w = tile[tx][ty];
    const _Float16 h = (_Float16)w;
    const _Float16 l = (_Float16)(w - (float)h);
    const size_t base = (size_t)(n0 + ty) * d.Kpad;
    d.dstHi[base + k0 + tx] = h;
    d.dstLo[base + k0 + tx] = l;
    if (d.Kpad != d.K && k0 + 16 == d.K) {
      d.dstHi[base + d.K + tx] = (_Float16)0.f;
      d.dstLo[base + d.K + tx] = (_Float16)0.f;
    }
  }
}

// ---------------------------------------------------------------------------
// x_bsd [B][L][C] -> x hi/lo [M][736] (pad cols zeroed)
__global__ __launch_bounds__(256) void k_xpose(const float* __restrict__ xbsd,
                                               _Float16* __restrict__ xhi,
                                               _Float16* __restrict__ xlo) {
  __shared__ float tile[16][17];
  const int b = blockIdx.z, l0 = blockIdx.x * 16, c0 = blockIdx.y * 16;
  const int tx = threadIdx.x, ty = threadIdx.y;
  tile[ty][tx] = xbsd[(size_t)b * LL * CC + (size_t)(l0 + ty) * CC + c0 + tx];
  __syncthreads();
  const float v = tile[tx][ty];
  const _Float16 h = (_Float16)v;
  const _Float16 l = (_Float16)(v - (float)h);
  const size_t m = (size_t)b * CC + c0 + ty;
  xhi[m * LLP + l0 + tx] = h;
  xlo[m * LLP + l0 + tx] = l;
  if (l0 == 704) {
    xhi[m * LLP + 720 + tx] = (_Float16)0.f;
    xlo[m * LLP + 720 + tx] = (_Float16)0.f;
  }
}

// ---------------------------------------------------------------------------
// Split-3 MFMA GEMM v4: BM=128, BN=64, BK=32; 256 threads = 4 waves (2x2).
// Staging via global_load_lds DMA (width 16) into DOUBLE-BUFFERED unpadded
// LDS; bank conflicts broken by XOR-swizzling the k-segment on the global
// address side (seg' = seg ^ ((row>>1)&3)) -> fragment reads are 2-way (free).
// One barrier per k-iter; DMA for k+1 issued right after the barrier overlaps
// the full compute phase. Weight buffers are over-allocated so edge-tile DMA
// reads stay in bounds (garbage flows only into cols discarded at epilogue).
// EPI: 0 = affine (dual s/t; out = Vin*vscale*exp(tanh(S)) + T)
//      1 = gelu  (single; hi/lo out)
//      2 = raw   (single; transposed fp32 out)
template<int EPI, bool DUAL, bool VIN16, bool OUT_T>
__global__ __launch_bounds__(256)
void k_gemm(const _Float16* Ahi, const _Float16* Alo, int lda,
            const _Float16* Whi, const _Float16* Wlo, int ldw,
            const float* Vin32, const _Float16* VinHi,
            const _Float16* VinLo, int ldv, float vscale,
            float* outT32,
            _Float16* outHi, _Float16* outLo, int ldo,
            int Kp, int Nv) {
  constexpr int NB   = DUAL ? 128 : 64;
  constexpr int ABUF = 128 * 32;            // halves per A plane
  constexpr int BBUF = NB * 32;             // halves per B plane
  constexpr int BUFH = 2 * ABUF + 2 * BBUF; // halves per buffer
  constexpr int NCH  = 16 + 2 * (NB / 16);  // DMA chunks (16 rows each)
  constexpr int NCHW = NCH / 4;             // chunks per wave
  __shared__ _Float16 smem[2 * BUFH];       // dual: 64 KB, single: 48 KB

  const int m0 = blockIdx.y * 128;
  const int n0 = blockIdx.x * 64;
  const int tid = threadIdx.x;
  const int w = tid >> 6, lane = tid & 63, q = lane >> 4, r = lane & 15;
  const int wr = (w & 1) * 64, wc = (w >> 1) * 32;
  const int lr = lane >> 2, ls = lane & 3;  // DMA lane decode: row-in-chunk, seg

  f32x4 accS[4][2] = {};
  f32x4 accT[4][2] = {};

  auto issue_dma = [&](int buf, int k0) {
    _Float16* base = &smem[buf * BUFH];
#pragma unroll
    for (int cc = 0; cc < NCHW; ++cc) {
      const int chunk = w * NCHW + cc;
      const _Float16* gsrc;
      _Float16* ldst;
      if (chunk < 8) {                       // A hi, rows [chunk*16, +16)
        const int rb = chunk * 16;
        const int R = rb + lr;
        const int ss = ls ^ ((R >> 1) & 3);
        gsrc = Ahi + (size_t)(m0 + R) * lda + k0 + ss * 8;
        ldst = base + rb * 32;
      } else if (chunk < 16) {               // A lo
        const int rb = (chunk - 8) * 16;
        const int R = rb + lr;
        const int ss = ls ^ ((R >> 1) & 3);
        gsrc = Alo + (size_t)(m0 + R) * lda + k0 + ss * 8;
        ldst = base + ABUF + rb * 32;
      } else if (chunk < 16 + NB / 16) {     // B hi
        const int rb = (chunk - 16) * 16;
        const int R = rb + lr;
        const int ss = ls ^ ((R >> 1) & 3);
        const int wrow = (R < 64) ? (n0 + R) : (Nv + n0 + (R - 64));
        gsrc = Whi + (size_t)wrow * ldw + k0 + ss * 8;
        ldst = base + 2 * ABUF + rb * 32;
      } else {                               // B lo
        const int rb = (chunk - 16 - NB / 16) * 16;
        const int R = rb + lr;
        const int ss = ls ^ ((R >> 1) & 3);
        const int wrow = (R < 64) ? (n0 + R) : (Nv + n0 + (R - 64));
        gsrc = Wlo + (size_t)wrow * ldw + k0 + ss * 8;
        ldst = base + 2 * ABUF + BBUF + rb * 32;
      }
      GLDS16(gsrc, ldst);
    }
  };

  issue_dma(0, 0);
  const int nk = Kp >> 5;
  for (int kc = 0; kc < nk; ++kc) {
    __syncthreads();                          // drains this buffer's DMA
    if (kc + 1 < nk) issue_dma((kc + 1) & 1, (kc + 1) << 5);

    const _Float16* base = &smem[(kc & 1) * BUFH];
    f16x8 ah[4], al[4];
#pragma unroll
    for (int rt = 0; rt < 4; ++rt) {
      const int R = wr + rt * 16 + r;
      const int t = (q ^ ((R >> 1) & 3)) * 8;
      ah[rt] = *(const f16x8*)(base + R * 32 + t);
      al[rt] = *(const f16x8*)(base + ABUF + R * 32 + t);
    }
#pragma unroll
    for (int ct = 0; ct < 2; ++ct) {
      const int RB = wc + ct * 16 + r;
      const int tb = (q ^ ((RB >> 1) & 3)) * 8;
      const f16x8 bh = *(const f16x8*)(base + 2 * ABUF + RB * 32 + tb);
      const f16x8 bl = *(const f16x8*)(base + 2 * ABUF + BBUF + RB * 32 + tb);
#pragma unroll
      for (int rt = 0; rt < 4; ++rt) {
        accS[rt][ct] = __builtin_amdgcn_mfma_f32_16x16x32_f16(ah[rt], bh, accS[rt][ct], 0, 0, 0);
        accS[rt][ct] = __builtin_amdgcn_mfma_f32_16x16x32_f16(al[rt], bh, accS[rt][ct], 0, 0, 0);
        accS[rt][ct] = __builtin_amdgcn_mfma_f32_16x16x32_f16(ah[rt], bl, accS[rt][ct], 0, 0, 0);
      }
      if (DUAL) {
        const int RT = 64 + RB;
        const int tt = (q ^ ((RT >> 1) & 3)) * 8;
        const f16x8 chh = *(const f16x8*)(base + 2 * ABUF + RT * 32 + tt);
        const f16x8 cll = *(const f16x8*)(base + 2 * ABUF + BBUF + RT * 32 + tt);
#pragma unroll
        for (int rt = 0; rt < 4; ++rt) {
          accT[rt][ct] = __builtin_amdgcn_mfma_f32_16x16x32_f16(ah[rt], chh, accT[rt][ct], 0, 0, 0);
          accT[rt][ct] = __builtin_amdgcn_mfma_f32_16x16x32_f16(al[rt], chh, accT[rt][ct], 0, 0, 0);
          accT[rt][ct] = __builtin_amdgcn_mfma_f32_16x16x32_f16(ah[rt], cll, accT[rt][ct], 0, 0, 0);
        }
      }
    }
  }

  // epilogue: m = m0 + wr + rt*16 + q*4 + g,  n = n0 + wc + ct*16 + r
#pragma unroll
  for (int rt = 0; rt < 4; ++rt) {
    const int mb = m0 + wr + rt * 16 + q * 4;
#pragma unroll
    for (int ct = 0; ct < 2; ++ct) {
      const int n = n0 + wc + ct * 16 + r;
      if (n >= Nv) continue;
      if (EPI == 2) {
        *(f32x4*)(outT32 + (size_t)n * MM + mb) = accS[rt][ct];
      } else if (EPI == 1) {
#pragma unroll
        for (int g = 0; g < 4; ++g) {
          const int m = mb + g;
          const float v = accS[rt][ct][g];
          const float o = 0.5f * v * (1.0f + tanhf(0.7978845608028654f * (v + 0.044715f * v * v * v)));
          const _Float16 h = (_Float16)o;
          outHi[(size_t)m * ldo + n] = h;
          outLo[(size_t)m * ldo + n] = (_Float16)(o - (float)h);
        }
      } else {
        f32x4 o;
#pragma unroll
        for (int g = 0; g < 4; ++g) {
          const int m = mb + g;
          float v;
          if (VIN16) {
            v = (float)VinHi[(size_t)m * ldv + n] + (float)VinLo[(size_t)m * ldv + n];
          } else {
            v = Vin32[(size_t)m * ldv + n];
          }
          const float s = expf(tanhf(accS[rt][ct][g]));
          o[g] = v * vscale * s + accT[rt][ct][g];
        }
        if (OUT_T) {
          *(f32x4*)(outT32 + (size_t)n * MM + mb) = o;
        } else {
#pragma unroll
          for (int g = 0; g < 4; ++g) {
            const int m = mb + g;
            const _Float16 h = (_Float16)o[g];
            outHi[(size_t)m * ldo + n] = h;
            outLo[(size_t)m * ldo + n] = (_Float16)(o[g] - (float)h);
          }
        }
      }
    }
  }
}

// ---------------------------------------------------------------------------
// Final elementwise: Pt[840][M] (theta raw | S raw | T), yT[336][M] -> out[B][336][C]
__global__ __launch_bounds__(256) void k_final(const float* __restrict__ Pt,
                                               const float* __restrict__ yT,
                                               const float* __restrict__ Ay,
                                               const float* __restrict__ By,
                                               float* __restrict__ out) {
  const int c = threadIdx.x;                       // 0..63
  const int j = blockIdx.x * 4 + threadIdx.y;      // 0..167
  const int b = blockIdx.y;
  const int m = b * 64 + c;
  const float th = 3.14159265358979323846f * tanhf(Pt[(size_t)j * MM + m]);
  const float sc0 = expf(tanhf(Pt[(size_t)(168 + 2 * j) * MM + m]));
  const float sc1 = expf(tanhf(Pt[(size_t)(169 + 2 * j) * MM + m]));
  const float t0 = Pt[(size_t)(504 + 2 * j) * MM + m];
  const float t1 = Pt[(size_t)(505 + 2 * j) * MM + m];
  const float re = yT[(size_t)(2 * j) * MM + m];
  const float im = yT[(size_t)(2 * j + 1) * MM + m];
  const float a = Ay[c * P2C + j], bb = By[c * P2C + j];
  const float rn = rsqrtf(a * a + bb * bb);
  const float ca = a * rn, cb = bb * rn;
  float s1v, c1;
  sincosf(th, &s1v, &c1);
  const float r1 = c1 * re - s1v * im, i1 = s1v * re + c1 * im;   // rot
  const float r2 = ca * r1 - cb * i1,  i2 = cb * r1 + ca * i1;    // koop
  const float r3 = r2 * sc0,           i3 = i2 * sc1;             // * scale
  const float r4 = ca * r3 + cb * i3,  i4 = ca * i3 - cb * r3;    // koop^-1
  const float r5 = c1 * r4 + s1v * i4, i5 = c1 * i4 - s1v * r4;   // rot^-1
  out[(size_t)b * PP * CC + (size_t)(2 * j) * CC + c]     = r5 + t0;
  out[(size_t)b * PP * CC + (size_t)(2 * j + 1) * CC + c] = i5 + t1;
}

// ---------------------------------------------------------------------------
extern "C" void kernel_launch(void* const* d_in, const int* in_sizes, int n_in,
                              void* d_out, int out_size, void* d_ws, size_t ws_size,
                              hipStream_t stream) {
  const float* x_bsd   = (const float*)d_in[0];
  const float* z0      = (const float*)d_in[1];
  const float* y0      = (const float*)d_in[2];
  const float* W_h     = (const float*)d_in[3];
  const float* W_ssz   = (const float*)d_in[4];
  const float* W_xz_v2 = (const float*)d_in[5];
  const float* W_xz_v3 = (const float*)d_in[6];
  const float* W_xz_v4 = (const float*)d_in[7];
  const float* W_xz_v5 = (const float*)d_in[8];
  const float* W_zx_v0 = (const float*)d_in[9];
  const float* W_zx_v2 = (const float*)d_in[10];
  const float* W_zx_v3 = (const float*)d_in[11];
  // d_in[12] = W_zx_v5: dead (x never read after), skipped
  const float* W_zy_v4 = (const float*)d_in[13];
  const float* W_rot   = (const float*)d_in[14];
  const float* W_koo   = (const float*)d_in[15];
  const float* a_y     = (const float*)d_in[16];
  const float* b_y     = (const float*)d_in[17];
  float* out = (float*)d_out;

  char* p = (char*)d_ws;
  auto alloc = [&](size_t bytes) -> void* {
    void* r = (void*)p; p += (bytes + 255) & ~(size_t)255; return r;
  };
  float*    yT  = (float*)alloc((size_t)PP * MM * 4);
  float*    Pt  = (float*)alloc((size_t)(P2C * 5) * MM * 4);  // 840 rows
  _Float16* xhi = (_Float16*)alloc((size_t)MM * LLP * 2);
  _Float16* xlo = (_Float16*)alloc((size_t)MM * LLP * 2);
  _Float16* zhi = (_Float16*)alloc((size_t)MM * DD * 2);
  _Float16* zlo = (_Float16*)alloc((size_t)MM * DD * 2);
  _Float16* hhi = (_Float16*)alloc((size_t)MM * HH * 2);
  _Float16* hlo = (_Float16*)alloc((size_t)MM * HH * 2);
  auto wpair = [&](size_t elems, _Float16** lo) -> _Float16* {
    _Float16* hi = (_Float16*)alloc(elems * 2);
    *lo = (_Float16*)alloc(elems * 2);
    return hi;
  };
  // Row counts padded so edge-tile DMA reads stay in-bounds:
  //  zx (Nv=720, grid 12): T rows reach 720+767 -> 1536 rows
  //  zy (Nv=336, grid 6):  T rows reach 336+383 -> 768 rows
  //  cat (Nv=840, grid 14): rows reach 895      -> 896 rows
  _Float16 *tWhL, *tWsszL, *tWxz2L, *tWxz3L, *tWxz4L, *tWxz5L;
  _Float16 *tWzx0L, *tWzx2L, *tWzx3L, *tWzyL, *tWcatL;
  _Float16* tWh   = wpair((size_t)HH * LLP, &tWhL);
  _Float16* tWssz = wpair((size_t)(2*DD) * DD, &tWsszL);
  _Float16* tWxz2 = wpair((size_t)(2*DD) * LLP, &tWxz2L);
  _Float16* tWxz3 = wpair((size_t)(2*DD) * LLP, &tWxz3L);
  _Float16* tWxz4 = wpair((size_t)(2*DD) * LLP, &tWxz4L);
  _Float16* tWxz5 = wpair((size_t)(2*DD) * LLP, &tWxz5L);
  _Float16* tWzx0 = wpair((size_t)1536 * DD, &tWzx0L);
  _Float16* tWzx2 = wpair((size_t)1536 * DD, &tWzx2L);
  _Float16* tWzx3 = wpair((size_t)1536 * DD, &tWzx3L);
  _Float16* tWzy  = wpair((size_t)768 * DD, &tWzyL);
  _Float16* tWcat = wpair((size_t)896 * DD, &tWcatL);   // [840 real][512]

  // ---- weight convert table
  WTab tab;
  int base = 0;
  auto put = [&](int i, const float* src, _Float16* dh, _Float16* dl,
                 int K, int N, int Kpad) {
    const int tN = (N + 15) / 16;
    tab.d[i] = WDesc{src, dh, dl, K, N, Kpad, base, tN};
    base += ((K + 15) / 16) * tN;
  };
  put(0,  W_h,     tWh,   tWhL,   LL, HH,   LLP);
  put(1,  W_ssz,   tWssz, tWsszL, DD, 2*DD, DD);
  put(2,  W_xz_v2, tWxz2, tWxz2L, LL, 2*DD, LLP);
  put(3,  W_xz_v3, tWxz3, tWxz3L, LL, 2*DD, LLP);
  put(4,  W_xz_v4, tWxz4, tWxz4L, LL, 2*DD, LLP);
  put(5,  W_xz_v5, tWxz5, tWxz5L, LL, 2*DD, LLP);
  put(6,  W_zx_v0, tWzx0, tWzx0L, DD, 2*LL, DD);
  put(7,  W_zx_v2, tWzx2, tWzx2L, DD, 2*LL, DD);
  put(8,  W_zx_v3, tWzx3, tWzx3L, DD, 2*LL, DD);
  put(9,  W_zy_v4, tWzy,  tWzyL,  DD, 2*PP, DD);
  put(10, W_rot,   tWcat, tWcatL, DD, P2C,  DD);
  put(11, W_koo,   tWcat + (size_t)P2C * DD, tWcatL + (size_t)P2C * DD, DD, 2*PP, DD);
  const int total_tiles = base;

  k_convert<<<dim3(total_tiles), dim3(256), 0, stream>>>(tab);
  k_xpose<<<dim3(45, 4, 64), dim3(16, 16), 0, stream>>>(x_bsd, xhi, xlo);

  const dim3 blk(256);
  // h = gelu(x @ W_h)
  k_gemm<1, false, false, false><<<dim3(8, 32), blk, 0, stream>>>(
      xhi, xlo, LLP, tWh, tWhL, LLP,
      nullptr, nullptr, nullptr, 0, 0.f, nullptr, hhi, hlo, HH, LLP, HH);
  // z = affine(z0*0.1, h, W_ssz)
  k_gemm<0, true, false, false><<<dim3(8, 32), blk, 0, stream>>>(
      hhi, hlo, HH, tWssz, tWsszL, DD,
      z0, nullptr, nullptr, DD, 0.1f, nullptr, zhi, zlo, DD, DD, DD);
  // x = affine(x, z, W_zx_v0)
  k_gemm<0, true, true, false><<<dim3(12, 32), blk, 0, stream>>>(
      zhi, zlo, DD, tWzx0, tWzx0L, DD,
      nullptr, xhi, xlo, LLP, 1.f, nullptr, xhi, xlo, LLP, DD, LL);
  // z = affine(z, x, W_xz_v2)
  k_gemm<0, true, true, false><<<dim3(8, 32), blk, 0, stream>>>(
      xhi, xlo, LLP, tWxz2, tWxz2L, LLP,
      nullptr, zhi, zlo, DD, 1.f, nullptr, zhi, zlo, DD, LLP, DD);
  // x = affine(x, z, W_zx_v2)
  k_gemm<0, true, true, false><<<dim3(12, 32), blk, 0, stream>>>(
      zhi, zlo, DD, tWzx2, tWzx2L, DD,
      nullptr, xhi, xlo, LLP, 1.f, nullptr, xhi, xlo, LLP, DD, LL);
  // z = affine(z, x, W_xz_v3)
  k_gemm<0, true, true, false><<<dim3(8, 32), blk, 0, stream>>>(
      xhi, xlo, LLP, tWxz3, tWxz3L, LLP,
      nullptr, zhi, zlo, DD, 1.f, nullptr, zhi, zlo, DD, LLP, DD);
  // x = affine(x, z, W_zx_v3)
  k_gemm<0, true, true, false><<<dim3(12, 32), blk, 0, stream>>>(
      zhi, zlo, DD, tWzx3, tWzx3L, DD,
      nullptr, xhi, xlo, LLP, 1.f, nullptr, xhi, xlo, LLP, DD, LL);
  // z = affine(z, x, W_xz_v4)
  k_gemm<0, true, true, false><<<dim3(8, 32), blk, 0, stream>>>(
      xhi, xlo, LLP, tWxz4, tWxz4L, LLP,
      nullptr, zhi, zlo, DD, 1.f, nullptr, zhi, zlo, DD, LLP, DD);
  // yT = affine(y0*0.1, z, W_zy_v4)  [transposed fp32 out]
  k_gemm<0, true, false, true><<<dim3(6, 32), blk, 0, stream>>>(
      zhi, zlo, DD, tWzy, tWzyL, DD,
      y0, nullptr, nullptr, PP, 0.1f, yT, nullptr, nullptr, 0, DD, PP);
  // z = affine(z, x, W_xz_v5)
  k_gemm<0, true, true, false><<<dim3(8, 32), blk, 0, stream>>>(
      xhi, xlo, LLP, tWxz5, tWxz5L, LLP,
      nullptr, zhi, zlo, DD, 1.f, nullptr, zhi, zlo, DD, LLP, DD);
  // Pt = z @ [W_rot | W_koo]  (raw, transposed fp32 out): 840 cols
  k_gemm<2, false, false, true><<<dim3(14, 32), blk, 0, stream>>>(
      zhi, zlo, DD, tWcat, tWcatL, DD,
      nullptr, nullptr, nullptr, 0, 0.f, Pt, nullptr, nullptr, 0, DD, P2C * 5);
  // final elementwise + transposed store
  k_final<<<dim3(42, 64), dim3(64, 4), 0, stream>>>(Pt, yT, a_y, b_y, out);
}

// Round 11
// 476.362 us; speedup vs baseline: 1.1864x; 1.0321x over previous
//
#include <hip/hip_runtime.h>
#include <hip/hip_bf16.h>
#include <math.h>

#define BB  64
#define CC  64
#define LL  720
#define LLP 736           // 720 padded to multiple of 32
#define DD  512
#define PP  336
#define P2C 168
#define HH  512
#define MM  (BB*CC)       // 4096

typedef _Float16 f16x8 __attribute__((ext_vector_type(8)));
typedef float    f32x4 __attribute__((ext_vector_type(4)));

#define GLDS16(g, l) __builtin_amdgcn_global_load_lds( \
    (const __attribute__((address_space(1))) void*)(g), \
    (__attribute__((address_space(3))) void*)(l), 16, 0, 0)

// ---------------------------------------------------------------------------
// Batched weight convert: fp32 W[K][N] -> fp16 hi/lo planes Wt[N][Kpad]
struct WDesc { const float* src; _Float16* dstHi; _Float16* dstLo;
               int K, N, Kpad, tbase, tilesN; };
struct WTab  { WDesc d[12]; };

__global__ __launch_bounds__(256) void k_convert(WTab tab) {
  __shared__ float tile[16][17];
  const int bid = blockIdx.x;
  int wi = 0;
#pragma unroll
  for (int i = 1; i < 12; ++i) if (bid >= tab.d[i].tbase) wi = i;
  const WDesc d = tab.d[wi];
  const int lt = bid - d.tbase;
  const int tk = lt / d.tilesN, tn = lt % d.tilesN;
  const int k0 = tk * 16, n0 = tn * 16;
  const int tx = threadIdx.x & 15, ty = threadIdx.x >> 4;
  float v = 0.f;
  if (n0 + tx < d.N) v = d.src[(size_t)(k0 + ty) * d.N + n0 + tx];
  tile[ty][tx] = v;
  __syncthreads();
  if (n0 + ty < d.N) {
    const float w = tile[tx][ty];
    const _Float16 h = (_Float16)w;
    const _Float16 l = (_Float16)(w - (float)h);
    const size_t base = (size_t)(n0 + ty) * d.Kpad;
    d.dstHi[base + k0 + tx] = h;
    d.dstLo[base + k0 + tx] = l;
    if (d.Kpad != d.K && k0 + 16 == d.K) {
      d.dstHi[base + d.K + tx] = (_Float16)0.f;
      d.dstLo[base + d.K + tx] = (_Float16)0.f;
    }
  }
}

// ---------------------------------------------------------------------------
// x_bsd [B][L][C] -> x hi/lo [M][736] (pad cols zeroed)
__global__ __launch_bounds__(256) void k_xpose(const float* __restrict__ xbsd,
                                               _Float16* __restrict__ xhi,
                                               _Float16* __restrict__ xlo) {
  __shared__ float tile[16][17];
  const int b = blockIdx.z, l0 = blockIdx.x * 16, c0 = blockIdx.y * 16;
  const int tx = threadIdx.x, ty = threadIdx.y;
  tile[ty][tx] = xbsd[(size_t)b * LL * CC + (size_t)(l0 + ty) * CC + c0 + tx];
  __syncthreads();
  const float v = tile[tx][ty];
  const _Float16 h = (_Float16)v;
  const _Float16 l = (_Float16)(v - (float)h);
  const size_t m = (size_t)b * CC + c0 + ty;
  xhi[m * LLP + l0 + tx] = h;
  xlo[m * LLP + l0 + tx] = l;
  if (l0 == 704) {
    xhi[m * LLP + 720 + tx] = (_Float16)0.f;
    xlo[m * LLP + 720 + tx] = (_Float16)0.f;
  }
}

// ---------------------------------------------------------------------------
// Split-3 MFMA GEMM v5: BM=64, BN=64, BK=32; 256 threads = 4 waves (2x2:
// wave owns 32 rows x 32 cols, dual S+T). SINGLE 24 KB (dual) LDS buffer,
// m97-style two-barrier loop; grid.y=64 gives 2-3.5 blocks/CU so the barrier
// vmcnt(0) drain of one block overlaps MFMA of co-resident blocks (m114).
// Staging is global_load_lds DMA (16B) with k-segment XOR swizzle on the
// global side -> 2-way-bank fragment reads (free).
// EPI: 0 = affine (dual s/t; out = Vin*vscale*exp(tanh(S)) + T)
//      1 = gelu  (single; hi/lo out)
//      2 = raw   (single; transposed fp32 out)
template<int EPI, bool DUAL, bool VIN16, bool OUT_T>
__global__ __launch_bounds__(256)
void k_gemm(const _Float16* Ahi, const _Float16* Alo, int lda,
            const _Float16* Whi, const _Float16* Wlo, int ldw,
            const float* Vin32, const _Float16* VinHi,
            const _Float16* VinLo, int ldv, float vscale,
            float* outT32,
            _Float16* outHi, _Float16* outLo, int ldo,
            int Kp, int Nv) {
  constexpr int NB   = DUAL ? 128 : 64;     // B rows staged (S [+T])
  constexpr int ABUF = 64 * 32;             // halves per A plane
  constexpr int BBUF = NB * 32;             // halves per B plane
  constexpr int NCH  = 8 + 2 * (NB / 16);   // DMA chunks of 16 rows
  constexpr int NCHW = NCH / 4;             // chunks per wave
  __shared__ _Float16 smem[2 * ABUF + 2 * BBUF];  // dual 24 KB, single 16 KB

  const int m0 = blockIdx.y * 64;
  const int n0 = blockIdx.x * 64;
  const int tid = threadIdx.x;
  const int w = tid >> 6, lane = tid & 63, q = lane >> 4, r = lane & 15;
  const int wr = (w & 1) * 32, wc = (w >> 1) * 32;
  const int lr = lane >> 2, ls = lane & 3;  // DMA lane decode

  f32x4 accS[2][2] = {};
  f32x4 accT[2][2] = {};

  const int nk = Kp >> 5;
  for (int kc = 0; kc < nk; ++kc) {
    const int k0 = kc << 5;
    // ---- issue DMA for this k-tile (wave-uniform LDS base per chunk)
#pragma unroll
    for (int cc = 0; cc < NCHW; ++cc) {
      const int chunk = w * NCHW + cc;
      const _Float16* gsrc;
      _Float16* ldst;
      if (chunk < 4) {                       // A hi
        const int rb = chunk * 16;
        const int R = rb + lr;
        const int ss = ls ^ ((R >> 1) & 3);
        gsrc = Ahi + (size_t)(m0 + R) * lda + k0 + ss * 8;
        ldst = smem + rb * 32;
      } else if (chunk < 8) {                // A lo
        const int rb = (chunk - 4) * 16;
        const int R = rb + lr;
        const int ss = ls ^ ((R >> 1) & 3);
        gsrc = Alo + (size_t)(m0 + R) * lda + k0 + ss * 8;
        ldst = smem + ABUF + rb * 32;
      } else if (chunk < 8 + NB / 16) {      // B hi
        const int rb = (chunk - 8) * 16;
        const int R = rb + lr;
        const int ss = ls ^ ((R >> 1) & 3);
        const int wrow = (R < 64) ? (n0 + R) : (Nv + n0 + (R - 64));
        gsrc = Whi + (size_t)wrow * ldw + k0 + ss * 8;
        ldst = smem + 2 * ABUF + rb * 32;
      } else {                               // B lo
        const int rb = (chunk - 8 - NB / 16) * 16;
        const int R = rb + lr;
        const int ss = ls ^ ((R >> 1) & 3);
        const int wrow = (R < 64) ? (n0 + R) : (Nv + n0 + (R - 64));
        gsrc = Wlo + (size_t)wrow * ldw + k0 + ss * 8;
        ldst = smem + 2 * ABUF + BBUF + rb * 32;
      }
      GLDS16(gsrc, ldst);
    }
    __syncthreads();                          // drain DMA (co-resident blocks hide it)

    f16x8 ah[2], al[2];
#pragma unroll
    for (int rt = 0; rt < 2; ++rt) {
      const int R = wr + rt * 16 + r;
      const int t = (q ^ ((R >> 1) & 3)) * 8;
      ah[rt] = *(const f16x8*)(smem + R * 32 + t);
      al[rt] = *(const f16x8*)(smem + ABUF + R * 32 + t);
    }
#pragma unroll
    for (int ct = 0; ct < 2; ++ct) {
      const int RB = wc + ct * 16 + r;
      const int tb = (q ^ ((RB >> 1) & 3)) * 8;
      const f16x8 bh = *(const f16x8*)(smem + 2 * ABUF + RB * 32 + tb);
      const f16x8 bl = *(const f16x8*)(smem + 2 * ABUF + BBUF + RB * 32 + tb);
#pragma unroll
      for (int rt = 0; rt < 2; ++rt) {
        accS[rt][ct] = __builtin_amdgcn_mfma_f32_16x16x32_f16(ah[rt], bh, accS[rt][ct], 0, 0, 0);
        accS[rt][ct] = __builtin_amdgcn_mfma_f32_16x16x32_f16(al[rt], bh, accS[rt][ct], 0, 0, 0);
        accS[rt][ct] = __builtin_amdgcn_mfma_f32_16x16x32_f16(ah[rt], bl, accS[rt][ct], 0, 0, 0);
      }
      if (DUAL) {
        const int RT = 64 + RB;
        const int tt = (q ^ ((RT >> 1) & 3)) * 8;
        const f16x8 chh = *(const f16x8*)(smem + 2 * ABUF + RT * 32 + tt);
        const f16x8 cll = *(const f16x8*)(smem + 2 * ABUF + BBUF + RT * 32 + tt);
#pragma unroll
        for (int rt = 0; rt < 2; ++rt) {
          accT[rt][ct] = __builtin_amdgcn_mfma_f32_16x16x32_f16(ah[rt], chh, accT[rt][ct], 0, 0, 0);
          accT[rt][ct] = __builtin_amdgcn_mfma_f32_16x16x32_f16(al[rt], chh, accT[rt][ct], 0, 0, 0);
          accT[rt][ct] = __builtin_amdgcn_mfma_f32_16x16x32_f16(ah[rt], cll, accT[rt][ct], 0, 0, 0);
        }
      }
    }
    __syncthreads();                          // all reads done before next DMA overwrite
  }

  // epilogue: m = m0 + wr + rt*16 + q*4 + g,  n = n0 + wc + ct*16 + r
#pragma unroll
  for (int rt = 0; rt < 2; ++rt) {
    const int mb = m0 + wr + rt * 16 + q * 4;
#pragma unroll
    for (int ct = 0; ct < 2; ++ct) {
      const int n = n0 + wc + ct * 16 + r;
      if (n >= Nv) continue;
      if (EPI == 2) {
        *(f32x4*)(outT32 + (size_t)n * MM + mb) = accS[rt][ct];
      } else if (EPI == 1) {
#pragma unroll
        for (int g = 0; g < 4; ++g) {
          const int m = mb + g;
          const float v = accS[rt][ct][g];
          const float o = 0.5f * v * (1.0f + tanhf(0.7978845608028654f * (v + 0.044715f * v * v * v)));
          const _Float16 h = (_Float16)o;
          outHi[(size_t)m * ldo + n] = h;
          outLo[(size_t)m * ldo + n] = (_Float16)(o - (float)h);
        }
      } else {
        f32x4 o;
#pragma unroll
        for (int g = 0; g < 4; ++g) {
          const int m = mb + g;
          float v;
          if (VIN16) {
            v = (float)VinHi[(size_t)m * ldv + n] + (float)VinLo[(size_t)m * ldv + n];
          } else {
            v = Vin32[(size_t)m * ldv + n];
          }
          const float s = expf(tanhf(accS[rt][ct][g]));
          o[g] = v * vscale * s + accT[rt][ct][g];
        }
        if (OUT_T) {
          *(f32x4*)(outT32 + (size_t)n * MM + mb) = o;
        } else {
#pragma unroll
          for (int g = 0; g < 4; ++g) {
            const int m = mb + g;
            const _Float16 h = (_Float16)o[g];
            outHi[(size_t)m * ldo + n] = h;
            outLo[(size_t)m * ldo + n] = (_Float16)(o[g] - (float)h);
          }
        }
      }
    }
  }
}

// ---------------------------------------------------------------------------
// Final elementwise: Pt[840][M] (theta raw | S raw | T), yT[336][M] -> out[B][336][C]
__global__ __launch_bounds__(256) void k_final(const float* __restrict__ Pt,
                                               const float* __restrict__ yT,
                                               const float* __restrict__ Ay,
                                               const float* __restrict__ By,
                                               float* __restrict__ out) {
  const int c = threadIdx.x;                       // 0..63
  const int j = blockIdx.x * 4 + threadIdx.y;      // 0..167
  const int b = blockIdx.y;
  const int m = b * 64 + c;
  const float th = 3.14159265358979323846f * tanhf(Pt[(size_t)j * MM + m]);
  const float sc0 = expf(tanhf(Pt[(size_t)(168 + 2 * j) * MM + m]));
  const float sc1 = expf(tanhf(Pt[(size_t)(169 + 2 * j) * MM + m]));
  const float t0 = Pt[(size_t)(504 + 2 * j) * MM + m];
  const float t1 = Pt[(size_t)(505 + 2 * j) * MM + m];
  const float re = yT[(size_t)(2 * j) * MM + m];
  const float im = yT[(size_t)(2 * j + 1) * MM + m];
  const float a = Ay[c * P2C + j], bb = By[c * P2C + j];
  const float rn = rsqrtf(a * a + bb * bb);
  const float ca = a * rn, cb = bb * rn;
  float s1v, c1;
  sincosf(th, &s1v, &c1);
  const float r1 = c1 * re - s1v * im, i1 = s1v * re + c1 * im;   // rot
  const float r2 = ca * r1 - cb * i1,  i2 = cb * r1 + ca * i1;    // koop
  const float r3 = r2 * sc0,           i3 = i2 * sc1;             // * scale
  const float r4 = ca * r3 + cb * i3,  i4 = ca * i3 - cb * r3;    // koop^-1
  const float r5 = c1 * r4 + s1v * i4, i5 = c1 * i4 - s1v * r4;   // rot^-1
  out[(size_t)b * PP * CC + (size_t)(2 * j) * CC + c]     = r5 + t0;
  out[(size_t)b * PP * CC + (size_t)(2 * j + 1) * CC + c] = i5 + t1;
}

// ---------------------------------------------------------------------------
extern "C" void kernel_launch(void* const* d_in, const int* in_sizes, int n_in,
                              void* d_out, int out_size, void* d_ws, size_t ws_size,
                              hipStream_t stream) {
  const float* x_bsd   = (const float*)d_in[0];
  const float* z0      = (const float*)d_in[1];
  const float* y0      = (const float*)d_in[2];
  const float* W_h     = (const float*)d_in[3];
  const float* W_ssz   = (const float*)d_in[4];
  const float* W_xz_v2 = (const float*)d_in[5];
  const float* W_xz_v3 = (const float*)d_in[6];
  const float* W_xz_v4 = (const float*)d_in[7];
  const float* W_xz_v5 = (const float*)d_in[8];
  const float* W_zx_v0 = (const float*)d_in[9];
  const float* W_zx_v2 = (const float*)d_in[10];
  const float* W_zx_v3 = (const float*)d_in[11];
  // d_in[12] = W_zx_v5: dead (x never read after), skipped
  const float* W_zy_v4 = (const float*)d_in[13];
  const float* W_rot   = (const float*)d_in[14];
  const float* W_koo   = (const float*)d_in[15];
  const float* a_y     = (const float*)d_in[16];
  const float* b_y     = (const float*)d_in[17];
  float* out = (float*)d_out;

  char* p = (char*)d_ws;
  auto alloc = [&](size_t bytes) -> void* {
    void* r = (void*)p; p += (bytes + 255) & ~(size_t)255; return r;
  };
  float*    yT  = (float*)alloc((size_t)PP * MM * 4);
  float*    Pt  = (float*)alloc((size_t)(P2C * 5) * MM * 4);  // 840 rows
  _Float16* xhi = (_Float16*)alloc((size_t)MM * LLP * 2);
  _Float16* xlo = (_Float16*)alloc((size_t)MM * LLP * 2);
  _Float16* zhi = (_Float16*)alloc((size_t)MM * DD * 2);
  _Float16* zlo = (_Float16*)alloc((size_t)MM * DD * 2);
  _Float16* hhi = (_Float16*)alloc((size_t)MM * HH * 2);
  _Float16* hlo = (_Float16*)alloc((size_t)MM * HH * 2);
  auto wpair = [&](size_t elems, _Float16** lo) -> _Float16* {
    _Float16* hi = (_Float16*)alloc(elems * 2);
    *lo = (_Float16*)alloc(elems * 2);
    return hi;
  };
  // Row counts padded so edge-tile DMA reads stay in-bounds.
  _Float16 *tWhL, *tWsszL, *tWxz2L, *tWxz3L, *tWxz4L, *tWxz5L;
  _Float16 *tWzx0L, *tWzx2L, *tWzx3L, *tWzyL, *tWcatL;
  _Float16* tWh   = wpair((size_t)HH * LLP, &tWhL);
  _Float16* tWssz = wpair((size_t)(2*DD) * DD, &tWsszL);
  _Float16* tWxz2 = wpair((size_t)(2*DD) * LLP, &tWxz2L);
  _Float16* tWxz3 = wpair((size_t)(2*DD) * LLP, &tWxz3L);
  _Float16* tWxz4 = wpair((size_t)(2*DD) * LLP, &tWxz4L);
  _Float16* tWxz5 = wpair((size_t)(2*DD) * LLP, &tWxz5L);
  _Float16* tWzx0 = wpair((size_t)1536 * DD, &tWzx0L);
  _Float16* tWzx2 = wpair((size_t)1536 * DD, &tWzx2L);
  _Float16* tWzx3 = wpair((size_t)1536 * DD, &tWzx3L);
  _Float16* tWzy  = wpair((size_t)768 * DD, &tWzyL);
  _Float16* tWcat = wpair((size_t)896 * DD, &tWcatL);   // [840 real][512]

  // ---- weight convert table
  WTab tab;
  int base = 0;
  auto put = [&](int i, const float* src, _Float16* dh, _Float16* dl,
                 int K, int N, int Kpad) {
    const int tN = (N + 15) / 16;
    tab.d[i] = WDesc{src, dh, dl, K, N, Kpad, base, tN};
    base += ((K + 15) / 16) * tN;
  };
  put(0,  W_h,     tWh,   tWhL,   LL, HH,   LLP);
  put(1,  W_ssz,   tWssz, tWsszL, DD, 2*DD, DD);
  put(2,  W_xz_v2, tWxz2, tWxz2L, LL, 2*DD, LLP);
  put(3,  W_xz_v3, tWxz3, tWxz3L, LL, 2*DD, LLP);
  put(4,  W_xz_v4, tWxz4, tWxz4L, LL, 2*DD, LLP);
  put(5,  W_xz_v5, tWxz5, tWxz5L, LL, 2*DD, LLP);
  put(6,  W_zx_v0, tWzx0, tWzx0L, DD, 2*LL, DD);
  put(7,  W_zx_v2, tWzx2, tWzx2L, DD, 2*LL, DD);
  put(8,  W_zx_v3, tWzx3, tWzx3L, DD, 2*LL, DD);
  put(9,  W_zy_v4, tWzy,  tWzyL,  DD, 2*PP, DD);
  put(10, W_rot,   tWcat, tWcatL, DD, P2C,  DD);
  put(11, W_koo,   tWcat + (size_t)P2C * DD, tWcatL + (size_t)P2C * DD, DD, 2*PP, DD);
  const int total_tiles = base;

  k_convert<<<dim3(total_tiles), dim3(256), 0, stream>>>(tab);
  k_xpose<<<dim3(45, 4, 64), dim3(16, 16), 0, stream>>>(x_bsd, xhi, xlo);

  const dim3 blk(256);
  // h = gelu(x @ W_h)
  k_gemm<1, false, false, false><<<dim3(8, 64), blk, 0, stream>>>(
      xhi, xlo, LLP, tWh, tWhL, LLP,
      nullptr, nullptr, nullptr, 0, 0.f, nullptr, hhi, hlo, HH, LLP, HH);
  // z = affine(z0*0.1, h, W_ssz)
  k_gemm<0, true, false, false><<<dim3(8, 64), blk, 0, stream>>>(
      hhi, hlo, HH, tWssz, tWsszL, DD,
      z0, nullptr, nullptr, DD, 0.1f, nullptr, zhi, zlo, DD, DD, DD);
  // x = affine(x, z, W_zx_v0)
  k_gemm<0, true, true, false><<<dim3(12, 64), blk, 0, stream>>>(
      zhi, zlo, DD, tWzx0, tWzx0L, DD,
      nullptr, xhi, xlo, LLP, 1.f, nullptr, xhi, xlo, LLP, DD, LL);
  // z = affine(z, x, W_xz_v2)
  k_gemm<0, true, true, false><<<dim3(8, 64), blk, 0, stream>>>(
      xhi, xlo, LLP, tWxz2, tWxz2L, LLP,
      nullptr, zhi, zlo, DD, 1.f, nullptr, zhi, zlo, DD, LLP, DD);
  // x = affine(x, z, W_zx_v2)
  k_gemm<0, true, true, false><<<dim3(12, 64), blk, 0, stream>>>(
      zhi, zlo, DD, tWzx2, tWzx2L, DD,
      nullptr, xhi, xlo, LLP, 1.f, nullptr, xhi, xlo, LLP, DD, LL);
  // z = affine(z, x, W_xz_v3)
  k_gemm<0, true, true, false><<<dim3(8, 64), blk, 0, stream>>>(
      xhi, xlo, LLP, tWxz3, tWxz3L, LLP,
      nullptr, zhi, zlo, DD, 1.f, nullptr, zhi, zlo, DD, LLP, DD);
  // x = affine(x, z, W_zx_v3)
  k_gemm<0, true, true, false><<<dim3(12, 64), blk, 0, stream>>>(
      zhi, zlo, DD, tWzx3, tWzx3L, DD,
      nullptr, xhi, xlo, LLP, 1.f, nullptr, xhi, xlo, LLP, DD, LL);
  // z = affine(z, x, W_xz_v4)
  k_gemm<0, true, true, false><<<dim3(8, 64), blk, 0, stream>>>(
      xhi, xlo, LLP, tWxz4, tWxz4L, LLP,
      nullptr, zhi, zlo, DD, 1.f, nullptr, zhi, zlo, DD, LLP, DD);
  // yT = affine(y0*0.1, z, W_zy_v4)  [transposed fp32 out]
  k_gemm<0, true, false, true><<<dim3(6, 64), blk, 0, stream>>>(
      zhi, zlo, DD, tWzy, tWzyL, DD,
      y0, nullptr, nullptr, PP, 0.1f, yT, nullptr, nullptr, 0, DD, PP);
  // z = affine(z, x, W_xz_v5)
  k_gemm<0, true, true, false><<<dim3(8, 64), blk, 0, stream>>>(
      xhi, xlo, LLP, tWxz5, tWxz5L, LLP,
      nullptr, zhi, zlo, DD, 1.f, nullptr, zhi, zlo, DD, LLP, DD);
  // Pt = z @ [W_rot | W_koo]  (raw, transposed fp32 out): 840 cols
  k_gemm<2, false, false, true><<<dim3(14, 64), blk, 0, stream>>>(
      zhi, zlo, DD, tWcat, tWcatL, DD,
      nullptr, nullptr, nullptr, 0, 0.f, Pt, nullptr, nullptr, 0, DD, P2C * 5);
  // final elementwise + transposed store
  k_final<<<dim3(42, 64), dim3(64, 4), 0, stream>>>(Pt, yT, a_y, b_y, out);
}